// Round 1
// baseline (252.907 us; speedup 1.0000x reference)
//
#include <hip/hip_runtime.h>

// Cutout: x [B,C,H,W] fp32, zero a LENGTH x LENGTH box centered at (cy[b], cx[b])
// across all channels. B=256, C=3, H=W=224, n_holes=1, LENGTH=16.
//
// Memory-bound streaming op. Floor: 154 MB read + 154 MB write ~= 49 us @ 6.3 TB/s
// (measured float4-copy ceiling, m13). Prior version: 1 float4/thread ~= 5 TB/s.
//
// This version: 7 float4 (112 B) per thread. Per plane: 12544 float4 =
// 7 blocks x 256 threads x 7 elems (exact). Each block covers exactly 32 rows
// (1792 float4 / 56 per row), so the <=16-row hole intersects at most 2 of the
// 7 blocks -> hole masking is behind a WAVE-UNIFORM branch; 5/7 blocks run a
// pure unrolled copy (loads batched 7-deep before stores for MLP).
// Nontemporal loads/stores: single-touch data, skip L2.

typedef float floatx4 __attribute__((ext_vector_type(4)));

#define B_ 256
#define C_ 3
#define H_ 224
#define W_ 224
#define HALF 8
#define W4_ (W_ / 4)                  // 56 float4 per row
#define PLANE4 (H_ * W4_)             // 12544 float4 per plane
#define K_ 7                          // float4 per thread
#define CHUNK (K_ * 256)              // 1792 float4 per block = 32 rows exactly
#define ROWS_PER_BLK (CHUNK / W4_)    // 32
#define BLOCKS_X (PLANE4 / CHUNK)     // 7, exact

__global__ __launch_bounds__(256) void cutout_kernel(
    const floatx4* __restrict__ x,
    const int* __restrict__ cy,
    const int* __restrict__ cx,
    floatx4* __restrict__ out) {
    const int plane = blockIdx.y;                 // b*C + c, uniform
    const int b = plane / C_;                     // uniform -> SALU
    const int tid = threadIdx.x;
    const long g0 = (long)plane * PLANE4 + blockIdx.x * CHUNK + tid;

    // Batch all 7 loads first: 7 outstanding 1KB-per-wave nontemporal loads.
    floatx4 v[K_];
#pragma unroll
    for (int k = 0; k < K_; ++k)
        v[k] = __builtin_nontemporal_load(&x[g0 + (long)k * 256]);

    const int cyb = cy[b];                        // uniform scalar loads
    const int cxb = cx[b];
    const int by0 = blockIdx.x * ROWS_PER_BLK;    // first row this block owns

    // Wave-uniform: does the hole's row range [cyb-8, cyb+8) touch our 32 rows?
    if (cyb + HALF > by0 && cyb - HALF < by0 + ROWS_PER_BLK) {
        const int yq = tid / W4_;                 // one magic-div per thread
        int y  = by0 + yq;
        int x4 = tid - yq * W4_;
        const int lo = cxb - HALF;
        const int hi = cxb + HALF;
        const int ylo = cyb - HALF;
#pragma unroll
        for (int k = 0; k < K_; ++k) {
            // y in [cyb-8, cyb+8) as one unsigned compare
            const bool yin = (unsigned)(y - ylo) < 16u;
            const int x0 = x4 * 4;
            v[k].x = (yin && x0     >= lo && x0     < hi) ? 0.0f : v[k].x;
            v[k].y = (yin && x0 + 1 >= lo && x0 + 1 < hi) ? 0.0f : v[k].y;
            v[k].z = (yin && x0 + 2 >= lo && x0 + 2 < hi) ? 0.0f : v[k].z;
            v[k].w = (yin && x0 + 3 >= lo && x0 + 3 < hi) ? 0.0f : v[k].w;
            // advance by 256 float4: 256 = 4*56 + 32
            x4 += 32; y += 4;
            if (x4 >= W4_) { x4 -= W4_; y += 1; }
        }
    }

#pragma unroll
    for (int k = 0; k < K_; ++k)
        __builtin_nontemporal_store(v[k], &out[g0 + (long)k * 256]);
}

extern "C" void kernel_launch(void* const* d_in, const int* in_sizes, int n_in,
                              void* d_out, int out_size, void* d_ws, size_t ws_size,
                              hipStream_t stream) {
    const floatx4* x  = (const floatx4*)d_in[0];
    const int*     cy = (const int*)d_in[1];   // [1, B]
    const int*     cx = (const int*)d_in[2];   // [1, B]
    floatx4* out = (floatx4*)d_out;

    dim3 grid(BLOCKS_X, B_ * C_);              // 7 x 768 = 5376 blocks
    cutout_kernel<<<grid, 256, 0, stream>>>(x, cy, cx, out);
}